// Round 13
// baseline (48.635 us; speedup 1.0000x reference)
//
#include <hip/hip_runtime.h>
#include <math.h>

#define TPB 256
#define NCLS 20
#define PPC 5
#define NB 16
#define N0 16384
#define N1 4096
#define RECSZ 32           // s[5], T1[25], cnt, pad
#define NRECS 7680         // 960 blocks x 8 waves
#define NBLKA 960          // 640 scale0 halves + 320 scale1
#define NBLKB 640

// ---------------- kernel 1: label downsample -> packed int8 ------------------------
__global__ void downsample_labels(const int* __restrict__ tgt,
                                  char* __restrict__ lab0, char* __restrict__ lab1) {
    const int q = blockIdx.x * blockDim.x + threadIdx.x;   // 81920 quads
    if (q < 65536) {                                       // scale0: 16 * 4096 quads
        const int b = q >> 12, r = q & 4095;
        const int i = r >> 5, j0 = (r & 31) << 2;
        const int* src = tgt + b * 262144 + (i << 2) * 512;
        char4 v;
        v.x = (char)(src[(j0 + 0) << 2] - 1);
        v.y = (char)(src[(j0 + 1) << 2] - 1);
        v.z = (char)(src[(j0 + 2) << 2] - 1);
        v.w = (char)(src[(j0 + 3) << 2] - 1);
        ((char4*)lab0)[q] = v;
    } else {                                               // scale1: 16 * 1024 quads
        const int k = q - 65536;
        const int b = k >> 10, r = k & 1023;
        const int i = r >> 4, j0 = (r & 15) << 2;
        const int* src = tgt + b * 262144 + (i << 3) * 512;
        char4 v;
        v.x = (char)(src[(j0 + 0) << 3] - 1);
        v.y = (char)(src[(j0 + 1) << 3] - 1);
        v.z = (char)(src[(j0 + 2) << 3] - 1);
        v.w = (char)(src[(j0 + 3) << 3] - 1);
        ((char4*)lab1)[k] = v;
    }
}

// ---------------- kernel A: block-staged 2-phase, 4KB-contiguous load instrs -------
// Per chunk (1024 px): 5 rows x 4KB, each loaded by ONE wave-instruction spanning
// 4KB contiguous (256 thr x float4). Double-buffered LDS, raw s_barrier (loads for
// chunk k+1 stay in flight across it). Branchless consume, +64-thread shift so the
// LDS relay is a real cross-wave exchange.
__global__ __launch_bounds__(TPB) void kA(const float* __restrict__ dist0,
                                          const float* __restrict__ dist1,
                                          const char* __restrict__ lab0,
                                          const char* __restrict__ lab1,
                                          float* __restrict__ recs) {
    __shared__ float lds[2][5632];         // 45056 B: rows r at r*1024, labels at 5120

    const int blk = blockIdx.x;
    const int tid = threadIdx.x, lane = tid & 63, w = tid >> 6;
    int scale, bc, half, nc;
    if (blk < 640) { scale = 0; bc = blk >> 1; half = blk & 1; nc = 8; }
    else           { scale = 1; bc = blk - 640; half = 0;      nc = 4; }
    const int b = bc / NCLS, c = bc % NCLS;
    const int N = scale ? N1 : N0;
    const float* dist = scale ? dist1 : dist0;
    const char* labB = (scale ? lab1 + b * N1 : lab0 + b * N0) + half * 8192;
    const float* base = dist + (size_t)(b * 100 + c * PPC) * N + half * 8192;

    const float4* g4 = (const float4*)base;
    const int*    gl = (const int*)labB;
    const int rs = N >> 2;                 // row stride in float4 units

    float s0 = 0.f, s1 = 0.f, s2 = 0.f, s3 = 0.f, s4 = 0.f, kc = 0.f;
    float T1[25];
#pragma unroll
    for (int i = 0; i < 25; ++i) T1[i] = 0.f;

    // prologue: chunk 0 in flight
    int    nl = gl[tid];
    float4 n0 = g4[tid],          n1 = g4[rs + tid],     n2 = g4[2 * rs + tid],
           n3 = g4[3 * rs + tid], n4 = g4[4 * rs + tid];

    const int u = (tid + 64) & 255;        // consume another wave's staged columns

    for (int ch = 0; ch < nc; ++ch) {
        const float4 r0 = n0, r1 = n1, r2 = n2, r3 = n3, r4 = n4;
        const int rl = nl;
        if (ch + 1 < nc) {                 // issue next chunk (stays in flight
            const int o = (ch + 1) * 256 + tid;        // across the barrier)
            nl = gl[o];
            n0 = g4[o];          n1 = g4[rs + o];      n2 = g4[2 * rs + o];
            n3 = g4[3 * rs + o]; n4 = g4[4 * rs + o];
        }
        __builtin_amdgcn_sched_barrier(0); // pin issues above the writes
        float* Lb = lds[ch & 1];
        ((float4*)(Lb))[tid]        = r0;  // compiler inserts counted vmcnt here
        ((float4*)(Lb + 1024))[tid] = r1;
        ((float4*)(Lb + 2048))[tid] = r2;
        ((float4*)(Lb + 3072))[tid] = r3;
        ((float4*)(Lb + 4096))[tid] = r4;
        ((int*)(Lb + 5120))[tid]    = rl;
        asm volatile("s_waitcnt lgkmcnt(0)" ::: "memory");
        __builtin_amdgcn_s_barrier();      // raw: no vmcnt drain
        __builtin_amdgcn_sched_barrier(0);

        const float4 v0 = ((const float4*)(Lb))[u];
        const float4 v1 = ((const float4*)(Lb + 1024))[u];
        const float4 v2 = ((const float4*)(Lb + 2048))[u];
        const float4 v3 = ((const float4*)(Lb + 3072))[u];
        const float4 v4 = ((const float4*)(Lb + 4096))[u];
        const int    LI = ((const int*)(Lb + 5120))[u];

#define SLOT(K, F)                                                               \
        {                                                                        \
            const float w_ = (((unsigned)(LI >> (8 * K)) & 0xffu) ==             \
                              (unsigned)c) ? 1.f : 0.f;                          \
            const float d0 = v0.F, d1 = v1.F, d2 = v2.F, d3 = v3.F, d4 = v4.F;   \
            const float e0 = __expf(d0) * w_, e1 = __expf(d1) * w_,              \
                        e2 = __expf(d2) * w_, e3 = __expf(d3) * w_,              \
                        e4 = __expf(d4) * w_;                                    \
            s0 += e0; s1 += e1; s2 += e2; s3 += e3; s4 += e4; kc += w_;          \
            T1[0]  = fmaf(e0, d0, T1[0]);  T1[1]  = fmaf(e0, d1, T1[1]);         \
            T1[2]  = fmaf(e0, d2, T1[2]);  T1[3]  = fmaf(e0, d3, T1[3]);         \
            T1[4]  = fmaf(e0, d4, T1[4]);                                        \
            T1[5]  = fmaf(e1, d0, T1[5]);  T1[6]  = fmaf(e1, d1, T1[6]);         \
            T1[7]  = fmaf(e1, d2, T1[7]);  T1[8]  = fmaf(e1, d3, T1[8]);         \
            T1[9]  = fmaf(e1, d4, T1[9]);                                        \
            T1[10] = fmaf(e2, d0, T1[10]); T1[11] = fmaf(e2, d1, T1[11]);        \
            T1[12] = fmaf(e2, d2, T1[12]); T1[13] = fmaf(e2, d3, T1[13]);        \
            T1[14] = fmaf(e2, d4, T1[14]);                                       \
            T1[15] = fmaf(e3, d0, T1[15]); T1[16] = fmaf(e3, d1, T1[16]);        \
            T1[17] = fmaf(e3, d2, T1[17]); T1[18] = fmaf(e3, d3, T1[18]);        \
            T1[19] = fmaf(e3, d4, T1[19]);                                       \
            T1[20] = fmaf(e4, d0, T1[20]); T1[21] = fmaf(e4, d1, T1[21]);        \
            T1[22] = fmaf(e4, d2, T1[22]); T1[23] = fmaf(e4, d3, T1[23]);        \
            T1[24] = fmaf(e4, d4, T1[24]);                                       \
        }
        SLOT(0, x) SLOT(1, y) SLOT(2, z) SLOT(3, w)
#undef SLOT
        // no trailing barrier: next write targets the other buffer, and the
        // write after that is ordered behind barrier(ch+1) > everyone's consume(ch)
    }

    // fixed butterfly reduction of 31 values (per wave)
#pragma unroll
    for (int d = 32; d >= 1; d >>= 1) {
        s0 += __shfl_xor(s0, d, 64); s1 += __shfl_xor(s1, d, 64);
        s2 += __shfl_xor(s2, d, 64); s3 += __shfl_xor(s3, d, 64);
        s4 += __shfl_xor(s4, d, 64); kc += __shfl_xor(kc, d, 64);
#pragma unroll
        for (int i = 0; i < 25; ++i) T1[i] += __shfl_xor(T1[i], d, 64);
    }

    if (lane == 0) {
        float* r = recs + (size_t)(blk * 8 + w) * RECSZ;
        r[0] = s0; r[1] = s1; r[2] = s2; r[3] = s3; r[4] = s4;
#pragma unroll
        for (int i = 0; i < 25; ++i) r[5 + i] = T1[i];
        r[30] = kc;
    }
}

// ---------------- kernel B: sum wave records -> per-(b,c,scale) pair sums ----------
// C[a][b] = U[a][b]/S_a - log(S_b); merging is a plain sum (no max rescale).
__global__ __launch_bounds__(64) void kB(const float* __restrict__ recs,
                                         float* __restrict__ psum,
                                         float* __restrict__ pcnt) {
    const int blk = blockIdx.x;            // 320 scale0 + 320 scale1
    const int lane = threadIdx.x;
    const int scale = (blk >= 320) ? 1 : 0;
    const int bc = blk - scale * 320;
    const int rbase = scale ? (5120 + bc * 8) : (bc * 16);
    const int nrec = scale ? 8 : 16;
    const int a = (lane < 25) ? lane / 5 : 0;
    const int bb = (lane < 25) ? lane % 5 : 0;

    float S = 0.f, U = 0.f, cnt = 0.f;
    if (lane < 5)
        for (int r = 0; r < nrec; ++r) S += recs[(size_t)(rbase + r) * RECSZ + lane];
    if (lane < 25)
        for (int r = 0; r < nrec; ++r) U += recs[(size_t)(rbase + r) * RECSZ + 5 + lane];
    if (lane == 0)
        for (int r = 0; r < nrec; ++r) cnt += recs[(size_t)(rbase + r) * RECSZ + 30];
    cnt = __shfl(cnt, 0, 64);

    const float lse = (lane < 5) ? logf(S) : 0.f;
    const float Sa    = __shfl(S, a, 64);
    const float lse_b = __shfl(lse, bb, 64);
    const float C = U / Sa - lse_b;        // valid on lanes 0..24

    float tot = 0.f;
#pragma unroll
    for (int j = 0; j < PPC; ++j)
#pragma unroll
        for (int k = j + 1; k < PPC; ++k) {
            const float Ejj = __shfl(C, j * 5 + j, 64);
            const float Ekk = __shfl(C, k * 5 + k, 64);
            const float Cjk = __shfl(C, j * 5 + k, 64);
            const float Ckj = __shfl(C, k * 5 + j, 64);
            tot += expf(-0.5f * (Ejj + Ekk - Cjk - Ckj));
        }
    if (lane == 0) {
        const bool ok = (cnt >= 2.f);
        psum[blk] = ok ? tot : 0.f;
        pcnt[blk] = ok ? 10.f : 0.f;
    }
}

// ---------------- kernel C: deterministic final reduction --------------------------
__global__ void finalize_kernel(const float* __restrict__ psum,
                                const float* __restrict__ pcnt,
                                float* __restrict__ out) {
    __shared__ float rs[TPB], rc[TPB];
    const int tid = threadIdx.x;
    float s = 0.f, c = 0.f;
    for (int i = tid; i < NBLKB; i += TPB) { s += psum[i]; c += pcnt[i]; }
    rs[tid] = s; rc[tid] = c;
    __syncthreads();
    for (int off = 128; off > 0; off >>= 1) {
        if (tid < off) { rs[tid] += rs[tid + off]; rc[tid] += rc[tid + off]; }
        __syncthreads();
    }
    if (tid == 0) out[0] = (rc[0] > 0.f) ? (rs[0] / rc[0]) : 0.f;
}

extern "C" void kernel_launch(void* const* d_in, const int* in_sizes, int n_in,
                              void* d_out, int out_size, void* d_ws, size_t ws_size,
                              hipStream_t stream) {
    const float* dist0 = (const float*)d_in[0];   // [16,100,128,128] f32
    const float* dist1 = (const float*)d_in[1];   // [16,100,64,64]   f32
    const int*   tgt   = (const int*)d_in[2];     // [16,512,512]     i32
    float* out = (float*)d_out;

    char*  lab0 = (char*)d_ws;                     // 262144 B
    char*  lab1 = lab0 + 262144;                   // 65536 B
    float* recs = (float*)(lab0 + 327680);         // 7680 * 32 floats = 983 KB
    float* psum = recs + (size_t)NRECS * RECSZ;
    float* pcnt = psum + NBLKB;

    downsample_labels<<<320, TPB, 0, stream>>>(tgt, lab0, lab1);
    kA<<<NBLKA, TPB, 0, stream>>>(dist0, dist1, lab0, lab1, recs);
    kB<<<NBLKB, 64, 0, stream>>>(recs, psum, pcnt);
    finalize_kernel<<<1, TPB, 0, stream>>>(psum, pcnt, out);
}

// Round 14
// 44.877 us; speedup vs baseline: 1.0837x; 1.0837x over previous
//
#include <hip/hip_runtime.h>
#include <math.h>

#define TPB 256
#define NCLS 20
#define PPC 5
#define NB 16
#define N0 16384
#define N1 4096
#define RECSZ 32           // s[5], T1[25], cnt, pad
#define NWA 3200           // 2560 scale0 (8 segs) + 640 scale1 (2 segs), 1 wave each
#define NBLKB 640

// ---------------- kernel 1: label downsample -> packed int8 ------------------------
__global__ void downsample_labels(const int* __restrict__ tgt,
                                  char* __restrict__ lab0, char* __restrict__ lab1) {
    const int q = blockIdx.x * blockDim.x + threadIdx.x;   // 81920 quads
    if (q < 65536) {                                       // scale0: 16 * 4096 quads
        const int b = q >> 12, r = q & 4095;
        const int i = r >> 5, j0 = (r & 31) << 2;
        const int* src = tgt + b * 262144 + (i << 2) * 512;
        char4 v;
        v.x = (char)(src[(j0 + 0) << 2] - 1);
        v.y = (char)(src[(j0 + 1) << 2] - 1);
        v.z = (char)(src[(j0 + 2) << 2] - 1);
        v.w = (char)(src[(j0 + 3) << 2] - 1);
        ((char4*)lab0)[q] = v;
    } else {                                               // scale1: 16 * 1024 quads
        const int k = q - 65536;
        const int b = k >> 10, r = k & 1023;
        const int i = r >> 4, j0 = (r & 15) << 2;
        const int* src = tgt + b * 262144 + (i << 3) * 512;
        char4 v;
        v.x = (char)(src[(j0 + 0) << 3] - 1);
        v.y = (char)(src[(j0 + 1) << 3] - 1);
        v.z = (char)(src[(j0 + 2) << 3] - 1);
        v.w = (char)(src[(j0 + 3) << 3] - 1);
        ((char4*)lab1)[k] = v;
    }
}

// ---------------- kernel A: r6 geometry + r9 branchless body -----------------------
// 1 wave per 2048-px segment, 8 quad-iterations, named 1-ahead prefetch.
// Branchless: w=(lab==c); s[p]=sum w*exp(d_p); T1[a][b]=sum w*exp(d_a)*d_b.
// No launch_bounds min-occupancy arg (r7/r8: it caps VGPR at 512/(2N) -> spills).
__global__ __launch_bounds__(64) void kA(const float* __restrict__ dist0,
                                         const float* __restrict__ dist1,
                                         const char* __restrict__ lab0,
                                         const char* __restrict__ lab1,
                                         float* __restrict__ recs) {
    const int blk = blockIdx.x;
    int scale, bc, seg;
    if (blk < 2560) { scale = 0; bc = blk >> 3; seg = blk & 7; }
    else            { const int k = blk - 2560; scale = 1; bc = k >> 1; seg = k & 1; }
    const int b = bc / NCLS, c = bc % NCLS;
    const int N = scale ? N1 : N0;
    const float* dist = scale ? dist1 : dist0;
    const char* lab = (scale ? lab1 + b * N1 : lab0 + b * N0) + seg * 2048;
    const float* base = dist + (size_t)(b * 100 + c * PPC) * N + seg * 2048;

    const int lane = threadIdx.x;
    const float4* r0 = (const float4*)(base);
    const float4* r1 = (const float4*)(base + N);
    const float4* r2 = (const float4*)(base + 2 * N);
    const float4* r3 = (const float4*)(base + 3 * N);
    const float4* r4 = (const float4*)(base + 4 * N);
    const char4* lab4 = (const char4*)lab;

    float s0 = 0.f, s1 = 0.f, s2 = 0.f, s3 = 0.f, s4 = 0.f, kc = 0.f;
    float T1[25];
#pragma unroll
    for (int i = 0; i < 25; ++i) T1[i] = 0.f;

    // current tile (named registers only)
    char4  cL = lab4[lane];
    float4 c0 = r0[lane], c1 = r1[lane], c2 = r2[lane], c3 = r3[lane], c4 = r4[lane];

#define SLOT(F)                                                                  \
    {                                                                            \
        const float w_ = ((int)cL.F == c) ? 1.f : 0.f;                           \
        const float d0 = c0.F, d1 = c1.F, d2 = c2.F, d3 = c3.F, d4 = c4.F;       \
        const float e0 = __expf(d0) * w_, e1 = __expf(d1) * w_,                  \
                    e2 = __expf(d2) * w_, e3 = __expf(d3) * w_,                  \
                    e4 = __expf(d4) * w_;                                        \
        s0 += e0; s1 += e1; s2 += e2; s3 += e3; s4 += e4; kc += w_;              \
        T1[0]  = fmaf(e0, d0, T1[0]);  T1[1]  = fmaf(e0, d1, T1[1]);             \
        T1[2]  = fmaf(e0, d2, T1[2]);  T1[3]  = fmaf(e0, d3, T1[3]);             \
        T1[4]  = fmaf(e0, d4, T1[4]);                                            \
        T1[5]  = fmaf(e1, d0, T1[5]);  T1[6]  = fmaf(e1, d1, T1[6]);             \
        T1[7]  = fmaf(e1, d2, T1[7]);  T1[8]  = fmaf(e1, d3, T1[8]);             \
        T1[9]  = fmaf(e1, d4, T1[9]);                                            \
        T1[10] = fmaf(e2, d0, T1[10]); T1[11] = fmaf(e2, d1, T1[11]);            \
        T1[12] = fmaf(e2, d2, T1[12]); T1[13] = fmaf(e2, d3, T1[13]);            \
        T1[14] = fmaf(e2, d4, T1[14]);                                           \
        T1[15] = fmaf(e3, d0, T1[15]); T1[16] = fmaf(e3, d1, T1[16]);            \
        T1[17] = fmaf(e3, d2, T1[17]); T1[18] = fmaf(e3, d3, T1[18]);            \
        T1[19] = fmaf(e3, d4, T1[19]);                                           \
        T1[20] = fmaf(e4, d0, T1[20]); T1[21] = fmaf(e4, d1, T1[21]);            \
        T1[22] = fmaf(e4, d2, T1[22]); T1[23] = fmaf(e4, d3, T1[23]);            \
        T1[24] = fmaf(e4, d4, T1[24]);                                           \
    }

#define ITER_PF(NI)                                                              \
    {                                                                            \
        const int ni = (NI) * 64 + lane;                                         \
        const char4  nL = lab4[ni];                                              \
        const float4 n0 = r0[ni], n1 = r1[ni], n2 = r2[ni],                      \
                     n3 = r3[ni], n4 = r4[ni];                                   \
        SLOT(x) SLOT(y) SLOT(z) SLOT(w)                                          \
        cL = nL; c0 = n0; c1 = n1; c2 = n2; c3 = n3; c4 = n4;                    \
    }

    ITER_PF(1)
    ITER_PF(2)
    ITER_PF(3)
    ITER_PF(4)
    ITER_PF(5)
    ITER_PF(6)
    ITER_PF(7)
    SLOT(x) SLOT(y) SLOT(z) SLOT(w)      // last tile, no prefetch
#undef ITER_PF
#undef SLOT

    // fixed butterfly reduction of 31 values (amortized over 2048 px)
#pragma unroll
    for (int d = 32; d >= 1; d >>= 1) {
        s0 += __shfl_xor(s0, d, 64); s1 += __shfl_xor(s1, d, 64);
        s2 += __shfl_xor(s2, d, 64); s3 += __shfl_xor(s3, d, 64);
        s4 += __shfl_xor(s4, d, 64); kc += __shfl_xor(kc, d, 64);
#pragma unroll
        for (int i = 0; i < 25; ++i) T1[i] += __shfl_xor(T1[i], d, 64);
    }

    if (lane == 0) {
        float* r = recs + (size_t)blk * RECSZ;
        r[0] = s0; r[1] = s1; r[2] = s2; r[3] = s3; r[4] = s4;
#pragma unroll
        for (int i = 0; i < 25; ++i) r[5 + i] = T1[i];
        r[30] = kc;
    }
}

// ---------------- kernel B: sum wave records -> per-(b,c,scale) pair sums ----------
// C[a][b] = U[a][b]/S_a - log(S_b); merging is a plain sum (no max rescale).
__global__ __launch_bounds__(64) void kB(const float* __restrict__ recs,
                                         float* __restrict__ psum,
                                         float* __restrict__ pcnt) {
    const int blk = blockIdx.x;            // 320 scale0 + 320 scale1
    const int lane = threadIdx.x;
    const int scale = (blk >= 320) ? 1 : 0;
    const int bc = blk - scale * 320;
    const int rbase = scale ? (2560 + bc * 2) : (bc * 8);
    const int nrec = scale ? 2 : 8;
    const int a = (lane < 25) ? lane / 5 : 0;
    const int bb = (lane < 25) ? lane % 5 : 0;

    float S = 0.f, U = 0.f, cnt = 0.f;
    if (lane < 5)
        for (int r = 0; r < nrec; ++r) S += recs[(size_t)(rbase + r) * RECSZ + lane];
    if (lane < 25)
        for (int r = 0; r < nrec; ++r) U += recs[(size_t)(rbase + r) * RECSZ + 5 + lane];
    if (lane == 0)
        for (int r = 0; r < nrec; ++r) cnt += recs[(size_t)(rbase + r) * RECSZ + 30];
    cnt = __shfl(cnt, 0, 64);

    const float lse = (lane < 5) ? logf(S) : 0.f;
    const float Sa    = __shfl(S, a, 64);
    const float lse_b = __shfl(lse, bb, 64);
    const float C = U / Sa - lse_b;        // valid on lanes 0..24

    float tot = 0.f;
#pragma unroll
    for (int j = 0; j < PPC; ++j)
#pragma unroll
        for (int k = j + 1; k < PPC; ++k) {
            const float Ejj = __shfl(C, j * 5 + j, 64);
            const float Ekk = __shfl(C, k * 5 + k, 64);
            const float Cjk = __shfl(C, j * 5 + k, 64);
            const float Ckj = __shfl(C, k * 5 + j, 64);
            tot += expf(-0.5f * (Ejj + Ekk - Cjk - Ckj));
        }
    if (lane == 0) {
        const bool ok = (cnt >= 2.f);
        psum[blk] = ok ? tot : 0.f;
        pcnt[blk] = ok ? 10.f : 0.f;
    }
}

// ---------------- kernel C: deterministic final reduction --------------------------
__global__ void finalize_kernel(const float* __restrict__ psum,
                                const float* __restrict__ pcnt,
                                float* __restrict__ out) {
    __shared__ float rs[TPB], rc[TPB];
    const int tid = threadIdx.x;
    float s = 0.f, c = 0.f;
    for (int i = tid; i < NBLKB; i += TPB) { s += psum[i]; c += pcnt[i]; }
    rs[tid] = s; rc[tid] = c;
    __syncthreads();
    for (int off = 128; off > 0; off >>= 1) {
        if (tid < off) { rs[tid] += rs[tid + off]; rc[tid] += rc[tid + off]; }
        __syncthreads();
    }
    if (tid == 0) out[0] = (rc[0] > 0.f) ? (rs[0] / rc[0]) : 0.f;
}

extern "C" void kernel_launch(void* const* d_in, const int* in_sizes, int n_in,
                              void* d_out, int out_size, void* d_ws, size_t ws_size,
                              hipStream_t stream) {
    const float* dist0 = (const float*)d_in[0];   // [16,100,128,128] f32
    const float* dist1 = (const float*)d_in[1];   // [16,100,64,64]   f32
    const int*   tgt   = (const int*)d_in[2];     // [16,512,512]     i32
    float* out = (float*)d_out;

    char*  lab0 = (char*)d_ws;                     // 262144 B
    char*  lab1 = lab0 + 262144;                   // 65536 B
    float* recs = (float*)(lab0 + 327680);         // 3200 * 32 floats = 409.6 KB
    float* psum = recs + (size_t)NWA * RECSZ;
    float* pcnt = psum + NBLKB;

    downsample_labels<<<320, TPB, 0, stream>>>(tgt, lab0, lab1);
    kA<<<NWA, 64, 0, stream>>>(dist0, dist1, lab0, lab1, recs);
    kB<<<NBLKB, 64, 0, stream>>>(recs, psum, pcnt);
    finalize_kernel<<<1, TPB, 0, stream>>>(psum, pcnt, out);
}